// Round 6
// baseline (1536.913 us; speedup 1.0000x reference)
//
#include <hip/hip_runtime.h>

#define T_LEN  4096
#define KS     16
#define NCHUNK 256      // T_LEN / 16
#define LEAD   6        // consumer lags producers by 6 chunks
#define SLOTS  8        // LDS ring slots
#define BU_PAD 20       // row stride in dwords

#define ALPHA_F 0.9048374180359595f
#define BETA_F  0.09516258196404048f
#define THETA_F 0.5f

// Full-wave (64-lane) max, result in ALL lanes. 4 fused DPP max levels, then
// permlane32_swap / permlane16_swap + max. Manual s_nop 1 before every
// DPP/permlane consumer (VALU->DPP needs 2 wait states; compiler can't see
// inside the asm block). Verbatim from the passing R3/R4/R5 kernels.
__device__ __forceinline__ float wave64_max_all(float v) {
  float m, t;
  asm("s_nop 1\n\t"
      "v_max_f32 %0, %2, %2 quad_perm:[1,0,3,2] row_mask:0xf bank_mask:0xf\n\t"
      "s_nop 1\n\t"
      "v_max_f32 %0, %0, %0 quad_perm:[2,3,0,1] row_mask:0xf bank_mask:0xf\n\t"
      "s_nop 1\n\t"
      "v_max_f32 %0, %0, %0 row_half_mirror row_mask:0xf bank_mask:0xf\n\t"
      "s_nop 1\n\t"
      "v_max_f32 %0, %0, %0 row_mirror row_mask:0xf bank_mask:0xf\n\t"
      "v_mov_b32 %1, %0\n\t"
      "s_nop 1\n\t"
      "v_permlane32_swap_b32 %1, %0\n\t"
      "s_nop 1\n\t"
      "v_max_f32 %0, %0, %1\n\t"
      "v_mov_b32 %1, %0\n\t"
      "s_nop 1\n\t"
      "v_permlane16_swap_b32 %1, %0\n\t"
      "s_nop 1\n\t"
      "v_max_f32 %0, %0, %1"
      : "=&v"(m), "=&v"(t)
      : "v"(v));
  return m;
}

__global__ __launch_bounds__(192, 1)
void convlif_wta_kernel(const float* __restrict__ x, const float* __restrict__ W,
                        float* __restrict__ out) {
  const int b    = blockIdx.x;
  const int wave = threadIdx.x >> 6;   // 0,1 = producers; 2 = consumer
  const int lane = threadIdx.x & 63;   // channel k

  __shared__ float bu_lds[SLOTS][64][BU_PAD];   // 40 KB

  float* outB = out + (size_t)b * 64 * T_LEN;

  if (wave < 2) {
    // ================= producers: zero-fill + causal conv ================
    float w[KS];
    {
      const float4* w4 = reinterpret_cast<const float4*>(W + lane * KS);
      #pragma unroll
      for (int q = 0; q < 4; ++q) {
        float4 a = w4[q];
        w[4*q+0] = a.x; w[4*q+1] = a.y; w[4*q+2] = a.z; w[4*q+3] = a.w;
      }
    }
    const float4* xv4 = reinterpret_cast<const float4*>(x + (size_t)b * T_LEN);

    for (int s = 0; s < NCHUNK + LEAD; ++s) {
      if (s < NCHUNK && (s & 1) == wave) {
        const int c  = s;
        const int tb = c * 16;

        // zero-fill this chunk's output region (row = lane, cols tb..tb+15).
        // Consumer's sparse 1.0 stores to these addresses happen >= LEAD
        // barriers later; the vmcnt(0) drain below orders them.
        {
          const float4 z = make_float4(0.f, 0.f, 0.f, 0.f);
          float4* zp = reinterpret_cast<float4*>(outB + (size_t)lane * T_LEN + tb);
          zp[0] = z; zp[1] = z; zp[2] = z; zp[3] = z;
        }

        // xf[m] = x[16c-16+m], m = 0..31 (x[<0] treated as 0)
        float xf[32];
        if (c == 0) {
          #pragma unroll
          for (int m = 0; m < 16; ++m) xf[m] = 0.0f;
        } else {
          const int b4 = 4 * c - 4;
          #pragma unroll
          for (int q = 0; q < 4; ++q) {
            float4 a = xv4[b4 + q];
            xf[4*q+0] = a.x; xf[4*q+1] = a.y; xf[4*q+2] = a.z; xf[4*q+3] = a.w;
          }
        }
        #pragma unroll
        for (int q = 0; q < 4; ++q) {
          float4 a = xv4[4*c + q];
          xf[16+4*q+0] = a.x; xf[16+4*q+1] = a.y;
          xf[16+4*q+2] = a.z; xf[16+4*q+3] = a.w;
        }

        // u[t=16c+i] = sum_j w[j]*x[t-15+j]; summation order identical to R5
        float u[16];
        #pragma unroll
        for (int i = 0; i < 16; ++i) {
          float acc = w[0] * xf[1 + i];
          #pragma unroll
          for (int j = 1; j < KS; ++j) acc = fmaf(w[j], xf[1 + i + j], acc);
          u[i] = BETA_F * acc;
        }

        float4* dst = reinterpret_cast<float4*>(&bu_lds[c & (SLOTS-1)][lane][0]);
        dst[0] = make_float4(u[0],  u[1],  u[2],  u[3]);
        dst[1] = make_float4(u[4],  u[5],  u[6],  u[7]);
        dst[2] = make_float4(u[8],  u[9],  u[10], u[11]);
        dst[3] = make_float4(u[12], u[13], u[14], u[15]);

        // ensure zero stores are committed before crossing the barrier
        asm volatile("s_waitcnt vmcnt(0)" ::: "memory");
      }
      __syncthreads();
    }
  } else {
    // ============ consumer: speculate-and-repair LIF + WTA ===============
    float v = 0.0f;
    float4 b0, b1, b2, b3;

    for (int s = 0; s < NCHUNK + LEAD; ++s) {
      if (s >= LEAD) {
        const int c  = s - LEAD;
        const int tb = c * 16;
        if (c == 0) {
          const float4* src = reinterpret_cast<const float4*>(&bu_lds[0][lane][0]);
          b0 = src[0]; b1 = src[1]; b2 = src[2]; b3 = src[3];
        }
        float bu[16] = { b0.x, b0.y, b0.z, b0.w,  b1.x, b1.y, b1.z, b1.w,
                         b2.x, b2.y, b2.z, b2.w,  b3.x, b3.y, b3.z, b3.w };

        // --- speculative no-reset trajectory (ops identical to serial R5) ---
        float cc[16];
        unsigned word = 0;
        {
          float vv = v;
          #pragma unroll
          for (int j = 0; j < 16; ++j) {
            vv = fmaf(ALPHA_F, vv, bu[j]);
            cc[j] = vv;
            unsigned long long mk = __ballot(vv >= THETA_F);
            word |= (mk != 0ull ? 1u : 0u) << j;
          }
        }

        // --- event loop: actual crossings are a subset of spec crossings ---
        while (word) {
          const int t1 = (int)__builtin_ctz(word);   // uniform scalar

          // csel = cc[t1] via static 4-level mux (no dynamic reg indexing)
          float t8[8], t4[4], t2[2];
          #pragma unroll
          for (int j = 0; j < 8; ++j) t8[j] = (t1 & 8) ? cc[j+8] : cc[j];
          #pragma unroll
          for (int j = 0; j < 4; ++j) t4[j] = (t1 & 4) ? t8[j+4] : t8[j];
          #pragma unroll
          for (int j = 0; j < 2; ++j) t2[j] = (t1 & 2) ? t4[j+2] : t4[j];
          float csel = (t1 & 1) ? t2[1] : t2[0];

          // winner (exact R5 logic: >=2 candidates -> max; else ctz)
          unsigned long long cand = __ballot(csel >= THETA_F);  // nonzero by invariant
          int wl;
          if ((cand & (cand - 1ull)) != 0ull) {
            float mx = wave64_max_all(csel);
            wl = __builtin_ctzll(__ballot(csel == mx));
          } else {
            wl = __builtin_ctzll(cand);
          }
          const bool isw = (lane == wl);
          if (isw) outB[(size_t)wl * T_LEN + (tb + t1)] = 1.0f;  // sparse spike

          // restart the exact trajectory from t1 with the reset applied.
          // Non-winner lanes recompute bitwise-identical values.
          float vw0 = isw ? (csel - THETA_F) : csel;  // state AT t1 (post-reset)
          float vw  = vw0;
          unsigned nword = 0;
          #pragma unroll
          for (int j = 0; j < 16; ++j) {
            float adv = fmaf(ALPHA_F, vw, bu[j]);
            const bool after = (j > t1);              // uniform scalar
            vw = after ? adv : vw;
            float cn = after ? vw : ((j == t1) ? vw0 : cc[j]);
            cc[j] = cn;
            unsigned long long mk2 = __ballot(cn >= THETA_F);
            nword |= ((after && mk2 != 0ull) ? 1u : 0u) << j;
          }
          word = nword;   // strictly clears bit t1 -> terminates
        }
        v = cc[15];

        if (c + 1 < NCHUNK) {
          const float4* src =
              reinterpret_cast<const float4*>(&bu_lds[(c + 1) & (SLOTS-1)][lane][0]);
          b0 = src[0]; b1 = src[1]; b2 = src[2]; b3 = src[3];
        }
      }
      __syncthreads();
    }
  }
}

extern "C" void kernel_launch(void* const* d_in, const int* in_sizes, int n_in,
                              void* d_out, int out_size, void* d_ws, size_t ws_size,
                              hipStream_t stream) {
  const float* x   = (const float*)d_in[0];
  const float* W   = (const float*)d_in[1];
  float*       out = (float*)d_out;
  convlif_wta_kernel<<<dim3(256), dim3(192), 0, stream>>>(x, W, out);
}

// Round 7
// 238.949 us; speedup vs baseline: 6.4320x; 6.4320x over previous
//
#include <hip/hip_runtime.h>

#define T_LEN  4096
#define KS     16
#define NCHUNK 256      // T_LEN / 16
#define LEAD   6        // consumer lags producers by 6 chunks
#define SLOTS  8        // LDS ring slots
#define BU_PAD 20       // bu row stride in dwords
#define TCOLS  68       // tile row stride in floats (16B-aligned rows)

#define ALPHA_F 0.9048374180359595f
#define BETA_F  0.09516258196404048f
#define THETA_F 0.5f

// Full-wave (64-lane) max, result in ALL lanes. 4 fused DPP max levels, then
// permlane32_swap / permlane16_swap + max. Manual s_nop 1 before every
// DPP/permlane consumer (VALU->DPP needs 2 wait states; compiler can't see
// inside the asm block). Verbatim from the passing R3/R4/R5 kernels.
__device__ __forceinline__ float wave64_max_all(float v) {
  float m, t;
  asm("s_nop 1\n\t"
      "v_max_f32 %0, %2, %2 quad_perm:[1,0,3,2] row_mask:0xf bank_mask:0xf\n\t"
      "s_nop 1\n\t"
      "v_max_f32 %0, %0, %0 quad_perm:[2,3,0,1] row_mask:0xf bank_mask:0xf\n\t"
      "s_nop 1\n\t"
      "v_max_f32 %0, %0, %0 row_half_mirror row_mask:0xf bank_mask:0xf\n\t"
      "s_nop 1\n\t"
      "v_max_f32 %0, %0, %0 row_mirror row_mask:0xf bank_mask:0xf\n\t"
      "v_mov_b32 %1, %0\n\t"
      "s_nop 1\n\t"
      "v_permlane32_swap_b32 %1, %0\n\t"
      "s_nop 1\n\t"
      "v_max_f32 %0, %0, %1\n\t"
      "v_mov_b32 %1, %0\n\t"
      "s_nop 1\n\t"
      "v_permlane16_swap_b32 %1, %0\n\t"
      "s_nop 1\n\t"
      "v_max_f32 %0, %0, %1"
      : "=&v"(m), "=&v"(t)
      : "v"(v));
  return m;
}

__global__ __launch_bounds__(192, 1)
void convlif_wta_kernel(const float* __restrict__ x, const float* __restrict__ W,
                        float* __restrict__ out) {
  const int b    = blockIdx.x;
  const int wave = threadIdx.x >> 6;   // 0,1 = producers(+flush); 2 = consumer
  const int lane = threadIdx.x & 63;   // channel k

  __shared__ float bu_lds[SLOTS][64][BU_PAD];   // 40 KB  (conv ring)
  __shared__ float tile[2][64][TCOLS];          // 34 KB  (spike tile, dbuf)

  float* outB = out + (size_t)b * 64 * T_LEN;

  if (wave < 2) {
    // ========== producers: causal conv + tile flush (no zero-fill!) ========
    float w[KS];
    {
      const float4* w4 = reinterpret_cast<const float4*>(W + lane * KS);
      #pragma unroll
      for (int q = 0; q < 4; ++q) {
        float4 a = w4[q];
        w[4*q+0] = a.x; w[4*q+1] = a.y; w[4*q+2] = a.z; w[4*q+3] = a.w;
      }
    }
    const float4* xv4 = reinterpret_cast<const float4*>(x + (size_t)b * T_LEN);

    for (int s = 0; s < NCHUNK + LEAD + 1; ++s) {
      if (s < NCHUNK && (s & 1) == wave) {
        const int c = s;
        // xf[m] = x[16c-16+m], m = 0..31 (x[<0] treated as 0)
        float xf[32];
        if (c == 0) {
          #pragma unroll
          for (int m = 0; m < 16; ++m) xf[m] = 0.0f;
        } else {
          const int b4 = 4 * c - 4;
          #pragma unroll
          for (int q = 0; q < 4; ++q) {
            float4 a = xv4[b4 + q];
            xf[4*q+0] = a.x; xf[4*q+1] = a.y; xf[4*q+2] = a.z; xf[4*q+3] = a.w;
          }
        }
        #pragma unroll
        for (int q = 0; q < 4; ++q) {
          float4 a = xv4[4*c + q];
          xf[16+4*q+0] = a.x; xf[16+4*q+1] = a.y;
          xf[16+4*q+2] = a.z; xf[16+4*q+3] = a.w;
        }

        // u[t=16c+i] = sum_j w[j]*x[t-15+j]; summation order identical to R5
        float u[16];
        #pragma unroll
        for (int i = 0; i < 16; ++i) {
          float acc = w[0] * xf[1 + i];
          #pragma unroll
          for (int j = 1; j < KS; ++j) acc = fmaf(w[j], xf[1 + i + j], acc);
          u[i] = BETA_F * acc;
        }

        float4* dst = reinterpret_cast<float4*>(&bu_lds[c & (SLOTS-1)][lane][0]);
        dst[0] = make_float4(u[0],  u[1],  u[2],  u[3]);
        dst[1] = make_float4(u[4],  u[5],  u[6],  u[7]);
        dst[2] = make_float4(u[8],  u[9],  u[10], u[11]);
        dst[3] = make_float4(u[12], u[13], u[14], u[15]);
      }

      // flush completed 64-step tile T at s = 4T+10 (consumer finished its
      // last chunk at s-1; barrier below orders LDS writes -> these reads).
      // Buffer reuse by the consumer starts at s = 4T+14 -> no overlap.
      if (s >= 10 && (s & 3) == 2) {
        const int T = (s - 10) >> 2;
        if (T < T_LEN / 64) {
          const int pl   = wave * 64 + lane;   // 0..127
          const int colq = (pl & 15) * 4;      // 0,4,...,60
          const int r0   = pl >> 4;            // 0..7
          const float* tb = &tile[T & 1][0][0];
          #pragma unroll
          for (int it = 0; it < 8; ++it) {
            const int r = r0 + it * 8;
            const float* src = tb + r * TCOLS + colq;
            float4 vq = make_float4(src[0], src[1], src[2], src[3]);
            *reinterpret_cast<float4*>(&outB[(size_t)r * T_LEN + T * 64 + colq]) = vq;
          }
        }
      }
      __syncthreads();
    }
  } else {
    // ================= consumer: serial LIF + WTA recurrence ==============
    float v = 0.0f;
    float4 b0, b1, b2, b3;

    for (int s = 0; s < NCHUNK + LEAD + 1; ++s) {
      if (s >= LEAD && s < NCHUNK + LEAD) {
        const int c = s - LEAD;
        if (c == 0) {
          const float4* src = reinterpret_cast<const float4*>(&bu_lds[0][lane][0]);
          b0 = src[0]; b1 = src[1]; b2 = src[2]; b3 = src[3];
        }
        float bu[16] = { b0.x, b0.y, b0.z, b0.w,  b1.x, b1.y, b1.z, b1.w,
                         b2.x, b2.y, b2.z, b2.w,  b3.x, b3.y, b3.z, b3.w };

        // per-chunk static tile row base; ds_write offsets are compile-time
        float* trow = &tile[(c >> 2) & 1][lane][(c & 3) * 16];

        #pragma unroll
        for (int i = 0; i < 16; ++i) {
          v = fmaf(ALPHA_F, v, bu[i]);          // same arithmetic as R5
          float sv = 0.0f;

          unsigned long long sp = __ballot(v >= THETA_F);
          if (sp != 0ull) {
            int wl;
            if ((sp & (sp - 1ull)) != 0ull) {
              // >=2 candidates: winner = first lane attaining the global max
              float m = wave64_max_all(v);
              unsigned long long eq = __ballot(v == m);
              wl = __builtin_ctzll(eq);
            } else {
              // exactly one lane >= theta: it IS the argmax (any tying lane
              // would also be >= theta); first-index trivially preserved
              wl = __builtin_ctzll(sp);
            }
            if (lane == wl) {
              sv = 1.0f;
              v  = v - THETA_F;                 // v - s*theta, exact
            }
          }
          trow[i] = sv;                         // dense tile write (1 ds_write)
        }

        // prefetch next chunk's bu (produced >= 1 barrier ago; slot safe)
        if (c + 1 < NCHUNK) {
          const float4* src =
              reinterpret_cast<const float4*>(&bu_lds[(c + 1) & (SLOTS-1)][lane][0]);
          b0 = src[0]; b1 = src[1]; b2 = src[2]; b3 = src[3];
        }
      }
      __syncthreads();
    }
  }
}

extern "C" void kernel_launch(void* const* d_in, const int* in_sizes, int n_in,
                              void* d_out, int out_size, void* d_ws, size_t ws_size,
                              hipStream_t stream) {
  const float* x   = (const float*)d_in[0];
  const float* W   = (const float*)d_in[1];
  float*       out = (float*)d_out;
  convlif_wta_kernel<<<dim3(256), dim3(192), 0, stream>>>(x, W, out);
}